// Round 11
// baseline (576.999 us; speedup 1.0000x reference)
//
#include <hip/hip_runtime.h>

#define N_NODES 50000
#define N_EDGES 800000
#define DIM 128
#define OUTD 47
#define NBK 196                          // dst buckets of 256 nodes
#define EPB 4096                         // edges per histogram/bin block
#define NBIN ((N_EDGES + EPB - 1) / EPB) // 196
#define XCVT_NB (N_NODES * DIM / 8 / 256) // 3125 blocks, 8 elems/thread
#define WFNB 19                          // weight-fragment tiles: 8 + 8 + 3
#define NB_LAY ((N_NODES + 63) / 64)     // 782 blocks; 4/CU x 256 CU = 1024 capacity >= 782

typedef __attribute__((ext_vector_type(8))) short v8s;
typedef __attribute__((ext_vector_type(8))) unsigned short v8u;
typedef __attribute__((ext_vector_type(4))) float v4f;
typedef __attribute__((ext_vector_type(2))) float v2f;

static __device__ __forceinline__ unsigned short f2bf(float f) {
    union { float f; unsigned int u; } v; v.f = f;
    unsigned int x = v.u;
    return (unsigned short)((x + 0x7fffu + ((x >> 16) & 1u)) >> 16); // RNE
}
static __device__ __forceinline__ unsigned char f2fp8(float f) {
    unsigned int pk = __builtin_amdgcn_cvt_pk_fp8_f32(f, f, 0, false);
    return (unsigned char)(pk & 0xffu);
}

// ---- manual all-resident grid barrier (counter zeroed by the PREVIOUS dispatch each iteration).
// __threadfence at agent scope emits the L2 writeback/invalidate needed across XCDs (gfx950
// per-XCD L2 non-coherent); acquire atomic load invalidates this CU's L1 + XCD L2 on exit.
static __device__ __forceinline__ void gbar(int* bar, int nb) {
    __syncthreads();
    if (threadIdx.x == 0) {
        __threadfence();                 // release: flush prior writes to coherent point
        atomicAdd(bar, 1);               // device-scope by default
        while (__hip_atomic_load(bar, __ATOMIC_ACQUIRE, __HIP_MEMORY_SCOPE_AGENT) < nb)
            __builtin_amdgcn_s_sleep(2);
        __threadfence();                 // acquire: invalidate stale lines
    }
    __syncthreads();
}

// ---------------- prep: x->bf16+fp8 | per-block bucket hist partials | weight fragment cvt ----------------
// Weights emitted PRE-SWIZZLED into MFMA B-fragment order (1KB contiguous per wave fragment read).
// Also zeroes the CSR barrier counter for this iteration (visible via dispatch boundary).
__global__ __launch_bounds__(256) void k_prep(const float* __restrict__ x,
                                              unsigned short* __restrict__ xb,
                                              unsigned int* __restrict__ x8,
                                              const int* __restrict__ dst,
                                              int* __restrict__ parts,
                                              const float* __restrict__ ws1, const float* __restrict__ wn1,
                                              const float* __restrict__ ws2, const float* __restrict__ wn2,
                                              const float* __restrict__ ws3, const float* __restrict__ wn3,
                                              unsigned short* __restrict__ wf1,
                                              unsigned short* __restrict__ wf2,
                                              unsigned short* __restrict__ wf3,
                                              int* __restrict__ bars) {
    __shared__ int hist[NBK];
    const int bx = blockIdx.x, tid = threadIdx.x;
    if (bx == 0 && tid == 0) bars[0] = 0; // csr barrier counter
    if (bx < XCVT_NB) {
        int i = bx * 256 + tid; // 8 elems per thread
        float4 v0 = ((const float4*)x)[i * 2];
        float4 v1 = ((const float4*)x)[i * 2 + 1];
        ushort4 o0, o1;
        o0.x = f2bf(v0.x); o0.y = f2bf(v0.y); o0.z = f2bf(v0.z); o0.w = f2bf(v0.w);
        o1.x = f2bf(v1.x); o1.y = f2bf(v1.y); o1.z = f2bf(v1.z); o1.w = f2bf(v1.w);
        ((ushort4*)xb)[i * 2] = o0;
        ((ushort4*)xb)[i * 2 + 1] = o1;
        unsigned int a = __builtin_amdgcn_cvt_pk_fp8_f32(v0.x, v0.y, 0, false);
        a = __builtin_amdgcn_cvt_pk_fp8_f32(v0.z, v0.w, a, true);
        unsigned int b = __builtin_amdgcn_cvt_pk_fp8_f32(v1.x, v1.y, 0, false);
        b = __builtin_amdgcn_cvt_pk_fp8_f32(v1.z, v1.w, b, true);
        uint2 o; o.x = a; o.y = b;
        ((uint2*)x8)[i] = o;
    } else if (bx < XCVT_NB + NBIN) {
        const int j = bx - XCVT_NB;
        for (int i = tid; i < NBK; i += 256) hist[i] = 0;
        __syncthreads();
        const int e0 = j * EPB;
        const int ecnt = min(EPB, N_EDGES - e0);
        for (int r = tid; r < ecnt; r += 256)
            atomicAdd(&hist[dst[e0 + r] >> 8], 1); // LDS only
        __syncthreads();
        for (int i = tid; i < NBK; i += 256) parts[j * NBK + i] = hist[i];
    } else {
        int b2 = bx - XCVT_NB - NBIN; // fragment tile
        const float *sw, *nw; unsigned short* ob; int t, J;
        if (b2 < 8)       { sw = ws1; nw = wn1; ob = wf1; t = b2;      J = DIM; }
        else if (b2 < 16) { sw = ws2; nw = wn2; ob = wf2; t = b2 - 8;  J = DIM; }
        else              { sw = ws3; nw = wn3; ob = wf3; t = b2 - 16; J = OUTD; }
        const int lane = tid & 63, cp = tid >> 6;
        const int j = t * 16 + (lane & 15);
        const int kb = (lane >> 4) * 8;
        #pragma unroll
        for (int c2 = 0; c2 < 2; ++c2) {
            int c = cp * 2 + c2;
            int k0 = c * 32 + kb;
            v8u o;
            #pragma unroll
            for (int i = 0; i < 8; ++i) {
                int k = k0 + i;
                float v = 0.f;
                if (j < J) v = (k < DIM) ? sw[j * DIM + k] : nw[j * DIM + (k - DIM)];
                o[i] = f2bf(v);
            }
            *(v8u*)(ob + ((size_t)((t * 8 + c) * 64 + lane)) * 8) = o;
        }
    }
}

// ---------------- csr: bin (chunk j) + grid barrier + place (bucket j), one dispatch ----------------
// Phase 2 reuses phase 1's in-LDS bucket prefix (baseL/totL) -- k_place's 196-iter parts loop
// and first scan deleted. 196 blocks trivially all-resident.
__global__ __launch_bounds__(256) void k_csr(const int* __restrict__ src,
                                             const int* __restrict__ dst,
                                             const int* __restrict__ parts,
                                             unsigned int* __restrict__ packed,
                                             int* __restrict__ row_ptr,
                                             int* __restrict__ src_sorted,
                                             int* __restrict__ bars) {
    __shared__ int s[256], gb[NBK], cnt[NBK], baseL[NBK], totL[NBK];
    __shared__ int hist[256], cur[256];
    const int t = threadIdx.x;
    const int j = blockIdx.x;
    if (j == 0 && t == 0) { bars[1] = 0; bars[2] = 0; } // layer barrier counters
    // ---- phase 1: bin chunk j ----
    int ct = 0, cp = 0;
    for (int i = 0; i < NBIN; ++i) {
        int v = (t < NBK) ? parts[i * NBK + t] : 0;
        if (i == j) cp = ct;
        ct += v;
    }
    s[t] = ct;
    __syncthreads();
    for (int off = 1; off < 256; off <<= 1) {
        int u = (t >= off) ? s[t - off] : 0;
        __syncthreads();
        s[t] += u;
        __syncthreads();
    }
    if (t < NBK) {
        baseL[t] = s[t] - ct; totL[t] = ct;           // survive to phase 2
        gb[t] = (s[t] - ct) + cp; cnt[t] = 0;         // bucket base + own-chunk offset
    }
    __syncthreads();
    {
        const int e0 = j * EPB;
        const int ecnt = min(EPB, N_EDGES - e0);
        for (int r = t; r < ecnt; r += 256) {
            int sv = src[e0 + r], d = dst[e0 + r];
            int b = d >> 8;
            int loc = atomicAdd(&cnt[b], 1); // LDS
            packed[gb[b] + loc] = ((unsigned int)sv << 8) | (unsigned int)(d & 255);
        }
    }
    gbar(&bars[0], NBIN);
    // ---- phase 2: place bucket j ----
    const int base = baseL[j], cb = totL[j];
    hist[t] = 0;
    __syncthreads();
    for (int i = t; i < cb; i += 256)
        atomicAdd(&hist[packed[base + i] & 255u], 1); // LDS, ~16 avg per counter
    __syncthreads();
    int v = hist[t];
    s[t] = v;
    __syncthreads();
    for (int off = 1; off < 256; off <<= 1) {
        int u = (t >= off) ? s[t - off] : 0;
        __syncthreads();
        s[t] += u;
        __syncthreads();
    }
    int excl = base + s[t] - v;
    int node = j * 256 + t;
    if (node < N_NODES) row_ptr[node] = excl;
    if (j == NBK - 1 && t == 255) row_ptr[N_NODES] = base + cb; // == N_EDGES
    cur[t] = excl;
    __syncthreads();
    for (int i = t; i < cb; i += 256) {
        unsigned int pkt = packed[base + i];
        int pos = atomicAdd(&cur[pkt & 255u], 1);
        src_sorted[pos] = (int)(pkt >> 8);
    }
}

// ---------------- merged 3-layer persistent kernel ----------------
// Self-features live in the LDS A-tile across layers (epilogue writes bf16 back into the
// swizzled tile) -- h1b/h2b HBM round-trips deleted. fp8 table ping-pongs h8a<->h8b; the
// grid barrier (all 782 blocks resident) separates layers like a dispatch boundary did.
static __device__ __forceinline__ void acc16(v2f* acc, uint4 u) {
    acc[0] += __builtin_amdgcn_cvt_pk_f32_fp8(u.x, false);
    acc[1] += __builtin_amdgcn_cvt_pk_f32_fp8(u.x, true);
    acc[2] += __builtin_amdgcn_cvt_pk_f32_fp8(u.y, false);
    acc[3] += __builtin_amdgcn_cvt_pk_f32_fp8(u.y, true);
    acc[4] += __builtin_amdgcn_cvt_pk_f32_fp8(u.z, false);
    acc[5] += __builtin_amdgcn_cvt_pk_f32_fp8(u.z, true);
    acc[6] += __builtin_amdgcn_cvt_pk_f32_fp8(u.w, false);
    acc[7] += __builtin_amdgcn_cvt_pk_f32_fp8(u.w, true);
}

template <int NT, bool RELU, bool FINAL>
static __device__ __forceinline__ void layer_phase(unsigned short* Alds, int m0,
                                                   const unsigned char* __restrict__ g8,
                                                   const int* __restrict__ row_ptr,
                                                   const int* __restrict__ srcs,
                                                   const unsigned short* __restrict__ Wf,
                                                   const float* __restrict__ bias,
                                                   float* __restrict__ outf,
                                                   unsigned char* __restrict__ out8,
                                                   int outdim) {
    const int tid = threadIdx.x;
    const int lane = tid & 63, wv = tid >> 6;
    const int gg = lane & 7;          // 8 lanes span the 128B fp8 row, 16B each
    const int sub = (lane >> 3) & 1;  // which edge of a pair this half handles
    const int ns = lane >> 4;         // node slot within wave
    for (int pass = 0; pass < 4; ++pass) {
        const int row = wv * 16 + pass * 4 + ns; // 0..63
        const int n = m0 + row;
        int start = 0, end = 0;
        if (n < N_NODES) { start = row_ptr[n]; end = row_ptr[n + 1]; }
        v2f ga[8] = {};
        int e = start;
        int s0, s1, s2, s3;
        bool have = (e + 8 <= end);
        if (have) {
            s0 = srcs[e + sub]; s1 = srcs[e + 2 + sub];
            s2 = srcs[e + 4 + sub]; s3 = srcs[e + 6 + sub];
        }
        while (have) {
            uint4 u0 = *(const uint4*)(g8 + (size_t)s0 * DIM + gg * 16);
            uint4 u1 = *(const uint4*)(g8 + (size_t)s1 * DIM + gg * 16);
            uint4 u2 = *(const uint4*)(g8 + (size_t)s2 * DIM + gg * 16);
            uint4 u3 = *(const uint4*)(g8 + (size_t)s3 * DIM + gg * 16);
            e += 8;
            have = (e + 8 <= end);
            if (have) { // prefetch next indices while gathers are in flight
                s0 = srcs[e + sub]; s1 = srcs[e + 2 + sub];
                s2 = srcs[e + 4 + sub]; s3 = srcs[e + 6 + sub];
            }
            acc16(ga, u0); acc16(ga, u1); acc16(ga, u2); acc16(ga, u3);
        }
        if (e + 4 <= end) {
            int t0 = srcs[e + sub], t1 = srcs[e + 2 + sub];
            uint4 u0 = *(const uint4*)(g8 + (size_t)t0 * DIM + gg * 16);
            uint4 u1 = *(const uint4*)(g8 + (size_t)t1 * DIM + gg * 16);
            acc16(ga, u0); acc16(ga, u1);
            e += 4;
        }
        if (e + 2 <= end) {
            int t0 = srcs[e + sub];
            uint4 u0 = *(const uint4*)(g8 + (size_t)t0 * DIM + gg * 16);
            acc16(ga, u0);
            e += 2;
        }
        if (e < end && sub == 0) { // odd leftover edge: even half only
            int t0 = srcs[e];
            uint4 u0 = *(const uint4*)(g8 + (size_t)t0 * DIM + gg * 16);
            acc16(ga, u0);
        }
        #pragma unroll
        for (int i = 0; i < 8; ++i) {
            ga[i][0] += __shfl_xor(ga[i][0], 8);
            ga[i][1] += __shfl_xor(ga[i][1], 8);
        }
        int d = end - start;
        float inv = (d > 0) ? 1.f / (float)d : 0.f;
        v2f w0 = sub ? ga[4] : ga[0];
        v2f w1 = sub ? ga[5] : ga[1];
        v2f w2 = sub ? ga[6] : ga[2];
        v2f w3 = sub ? ga[7] : ga[3];
        v8u o;
        o[0] = f2bf(w0[0] * inv); o[1] = f2bf(w0[1] * inv);
        o[2] = f2bf(w1[0] * inv); o[3] = f2bf(w1[1] * inv);
        o[4] = f2bf(w2[0] * inv); o[5] = f2bf(w2[1] * inv);
        o[6] = f2bf(w3[0] * inv); o[7] = f2bf(w3[1] * inv);
        *(v8u*)(Alds + row * 256 + ((DIM + gg * 16 + sub * 8) ^ ((row & 7) * 8))) = o;
    }
    __syncthreads();
    // ---- MFMA: A from LDS, W fragments streamed from L2 ----
    const int m = lane & 15, qd = lane >> 4;
    const int arow = wv * 16 + m;
    v4f acc[NT] = {};
    #pragma unroll
    for (int c = 0; c < 8; ++c) {
        const int koff = c * 32 + qd * 8;
        v8s af = *(const v8s*)(Alds + arow * 256 + (koff ^ ((arow & 7) * 8)));
        #pragma unroll
        for (int t = 0; t < NT; ++t) {
            v8s wf = *(const v8s*)(Wf + ((size_t)((t * 8 + c) * 64 + lane)) * 8);
            acc[t] = __builtin_amdgcn_mfma_f32_16x16x32_bf16(af, wf, acc[t], 0, 0, 0);
        }
    }
    __syncthreads(); // all MFMA reads of Alds done before epilogue writes the self half
    // ---- epilogue: FINAL -> fp32 global; else fp8 table + bf16 back into LDS self half ----
    #pragma unroll
    for (int t = 0; t < NT; ++t) {
        int col = t * 16 + m;
        bool colok = (col < outdim);
        float bv = colok ? bias[col] : 0.f;
        #pragma unroll
        for (int r = 0; r < 4; ++r) {
            int lrow = wv * 16 + qd * 4 + r;
            int nrow = m0 + lrow;
            if (colok && nrow < N_NODES) {
                float v = acc[t][r] + bv;
                if (RELU) v = fmaxf(v, 0.f);
                if (FINAL) {
                    outf[(size_t)nrow * outdim + col] = v;
                } else {
                    out8[(size_t)nrow * DIM + col] = f2fp8(v);
                    int gsh = (col & 0x78); // 8-short granule base
                    Alds[lrow * 256 + (gsh ^ ((lrow & 7) * 8)) + (col & 7)] = f2bf(v);
                }
            }
        }
    }
}

__global__ __launch_bounds__(256, 4) void k_layers(const unsigned short* __restrict__ xb,
                                                   unsigned char* __restrict__ h8a,
                                                   unsigned char* __restrict__ h8b,
                                                   const int* __restrict__ row_ptr,
                                                   const int* __restrict__ srcs,
                                                   const unsigned short* __restrict__ wf1,
                                                   const unsigned short* __restrict__ wf2,
                                                   const unsigned short* __restrict__ wf3,
                                                   const float* __restrict__ b1,
                                                   const float* __restrict__ b2,
                                                   const float* __restrict__ b3,
                                                   float* __restrict__ d_out,
                                                   int* __restrict__ bars) {
    __shared__ unsigned short Alds[64 * 256]; // 32 KB: [row][0..128)=self, [128..256)=mean, XOR-swizzled
    const int tid = threadIdx.x;
    const int m0 = blockIdx.x * 64;
    // ---- stage layer-1 self half from xb ----
    #pragma unroll
    for (int i = 0; i < 4; ++i) {
        int t = tid + 256 * i;           // 0..1023
        int row = t >> 4, ch = t & 15;   // 64 rows x 16 chunks of 8 shorts
        int node = m0 + row; if (node >= N_NODES) node = N_NODES - 1;
        v8u v = *(const v8u*)(xb + (size_t)node * DIM + ch * 8);
        *(v8u*)(Alds + row * 256 + ((ch * 8) ^ ((row & 7) * 8))) = v;
    }
    // layer 1: gather h8a, write fp8 h8b + self into LDS
    layer_phase<8, true, false>(Alds, m0, h8a, row_ptr, srcs, wf1, b1, nullptr, h8b, DIM);
    gbar(&bars[1], NB_LAY);
    // layer 2: gather h8b, write fp8 h8a + self into LDS
    layer_phase<8, true, false>(Alds, m0, h8b, row_ptr, srcs, wf2, b2, nullptr, h8a, DIM);
    gbar(&bars[2], NB_LAY);
    // layer 3: gather h8a, write fp32 output
    layer_phase<3, false, true>(Alds, m0, h8a, row_ptr, srcs, wf3, b3, d_out, nullptr, OUTD);
}

extern "C" void kernel_launch(void* const* d_in, const int* in_sizes, int n_in,
                              void* d_out, int out_size, void* d_ws, size_t ws_size,
                              hipStream_t stream) {
    const float* x   = (const float*)d_in[0];
    const int*   src = (const int*)d_in[1];
    const int*   dst = (const int*)d_in[2];
    const float* ws1 = (const float*)d_in[3];
    const float* wn1 = (const float*)d_in[4];
    const float* b1  = (const float*)d_in[5];
    const float* ws2 = (const float*)d_in[6];
    const float* wn2 = (const float*)d_in[7];
    const float* b2  = (const float*)d_in[8];
    const float* ws3 = (const float*)d_in[9];
    const float* wn3 = (const float*)d_in[10];
    const float* b3  = (const float*)d_in[11];

    char* p = (char*)d_ws;
    auto alloc = [&](size_t bytes) { char* r = p; p += (bytes + 255) & ~(size_t)255; return r; };
    int*   row_ptr = (int*)alloc((size_t)(N_NODES + 1) * 4);
    int*   srcs    = (int*)alloc((size_t)N_EDGES * 4);
    unsigned int* packed = (unsigned int*)alloc((size_t)N_EDGES * 4);
    int*   parts   = (int*)alloc((size_t)NBIN * NBK * 4);
    unsigned short* xb  = (unsigned short*)alloc((size_t)N_NODES * DIM * 2);
    unsigned char*  h8a = (unsigned char*)alloc((size_t)N_NODES * DIM);
    unsigned char*  h8b = (unsigned char*)alloc((size_t)N_NODES * DIM);
    unsigned short* wf1 = (unsigned short*)alloc((size_t)8 * 8 * 64 * 8 * 2);
    unsigned short* wf2 = (unsigned short*)alloc((size_t)8 * 8 * 64 * 8 * 2);
    unsigned short* wf3 = (unsigned short*)alloc((size_t)3 * 8 * 64 * 8 * 2);
    int*   bars = (int*)alloc(256); // [0]=csr, [1..2]=layer barriers

    // 1: conversions + bucket hist partials (+ zero csr barrier)
    k_prep<<<XCVT_NB + NBIN + WFNB, 256, 0, stream>>>(
        x, xb, (unsigned int*)h8a, dst, parts,
        ws1, wn1, ws2, wn2, ws3, wn3, wf1, wf2, wf3, bars);
    // 2: CSR build in one dispatch (bin + grid barrier + place; zeroes layer barriers)
    k_csr<<<NBIN, 256, 0, stream>>>(src, dst, parts, packed, row_ptr, srcs, bars);
    // 3: all three layers, persistent (2 grid barriers; self stays in LDS; fp8 ping-pong)
    k_layers<<<NB_LAY, 256, 0, stream>>>(xb, h8a, h8b, row_ptr, srcs,
                                         wf1, wf2, wf3, b1, b2, b3,
                                         (float*)d_out, bars);
}

// Round 17
// 245.134 us; speedup vs baseline: 2.3538x; 2.3538x over previous
//
#include <hip/hip_runtime.h>

#define N_NODES 50000
#define N_EDGES 800000
#define DIM 128
#define OUTD 47
#define NBK 196                          // dst buckets of 256 nodes
#define EPB 4096                         // edges per histogram/bin block
#define NBIN ((N_EDGES + EPB - 1) / EPB) // 196
#define XCVT_NB (N_NODES * DIM / 8 / 256) // 3125 blocks, 8 elems/thread
#define WFNB 19                          // weight-fragment tiles: 8 + 8 + 3

typedef __attribute__((ext_vector_type(8))) short v8s;
typedef __attribute__((ext_vector_type(8))) unsigned short v8u;
typedef __attribute__((ext_vector_type(4))) float v4f;
typedef __attribute__((ext_vector_type(2))) float v2f;

static __device__ __forceinline__ unsigned short f2bf(float f) {
    union { float f; unsigned int u; } v; v.f = f;
    unsigned int x = v.u;
    return (unsigned short)((x + 0x7fffu + ((x >> 16) & 1u)) >> 16); // RNE
}
static __device__ __forceinline__ unsigned char f2fp8(float f) {
    unsigned int pk = __builtin_amdgcn_cvt_pk_fp8_f32(f, f, 0, false);
    return (unsigned char)(pk & 0xffu);
}

// ---------------- prep: x->bf16+fp8 | per-block bucket hist partials | weight fragment cvt ----------------
// Weights emitted PRE-SWIZZLED into MFMA B-fragment order:
//   frag(t, c): lane l holds W[j = t*16 + (l&15)][k = c*32 + (l>>4)*8 + i], i=0..7 (bf16 x8, 16B)
//   stored at ob[((t*8 + c)*64 + l)*8 + i]  -> a wave's fragment read is 1KB contiguous.
__global__ __launch_bounds__(256) void k_prep(const float* __restrict__ x,
                                              unsigned short* __restrict__ xb,
                                              unsigned int* __restrict__ x8,
                                              const int* __restrict__ dst,
                                              int* __restrict__ parts,
                                              const float* __restrict__ ws1, const float* __restrict__ wn1,
                                              const float* __restrict__ ws2, const float* __restrict__ wn2,
                                              const float* __restrict__ ws3, const float* __restrict__ wn3,
                                              unsigned short* __restrict__ wf1,
                                              unsigned short* __restrict__ wf2,
                                              unsigned short* __restrict__ wf3) {
    __shared__ int hist[NBK];
    const int bx = blockIdx.x, tid = threadIdx.x;
    if (bx < XCVT_NB) {
        int i = bx * 256 + tid; // 8 elems per thread
        float4 v0 = ((const float4*)x)[i * 2];
        float4 v1 = ((const float4*)x)[i * 2 + 1];
        ushort4 o0, o1;
        o0.x = f2bf(v0.x); o0.y = f2bf(v0.y); o0.z = f2bf(v0.z); o0.w = f2bf(v0.w);
        o1.x = f2bf(v1.x); o1.y = f2bf(v1.y); o1.z = f2bf(v1.z); o1.w = f2bf(v1.w);
        ((ushort4*)xb)[i * 2] = o0;
        ((ushort4*)xb)[i * 2 + 1] = o1;
        unsigned int a = __builtin_amdgcn_cvt_pk_fp8_f32(v0.x, v0.y, 0, false);
        a = __builtin_amdgcn_cvt_pk_fp8_f32(v0.z, v0.w, a, true);
        unsigned int b = __builtin_amdgcn_cvt_pk_fp8_f32(v1.x, v1.y, 0, false);
        b = __builtin_amdgcn_cvt_pk_fp8_f32(v1.z, v1.w, b, true);
        uint2 o; o.x = a; o.y = b;
        ((uint2*)x8)[i] = o;
    } else if (bx < XCVT_NB + NBIN) {
        const int j = bx - XCVT_NB;
        for (int i = tid; i < NBK; i += 256) hist[i] = 0;
        __syncthreads();
        const int e0 = j * EPB;
        const int ecnt = min(EPB, N_EDGES - e0);
        for (int r = tid; r < ecnt; r += 256)
            atomicAdd(&hist[dst[e0 + r] >> 8], 1); // LDS only
        __syncthreads();
        for (int i = tid; i < NBK; i += 256) parts[j * NBK + i] = hist[i];
    } else {
        int b2 = bx - XCVT_NB - NBIN; // fragment tile
        const float *sw, *nw; unsigned short* ob; int t, J;
        if (b2 < 8)       { sw = ws1; nw = wn1; ob = wf1; t = b2;      J = DIM; }
        else if (b2 < 16) { sw = ws2; nw = wn2; ob = wf2; t = b2 - 8;  J = DIM; }
        else              { sw = ws3; nw = wn3; ob = wf3; t = b2 - 16; J = OUTD; }
        const int lane = tid & 63, cp = tid >> 6;
        const int j = t * 16 + (lane & 15);
        const int kb = (lane >> 4) * 8;
        #pragma unroll
        for (int c2 = 0; c2 < 2; ++c2) {
            int c = cp * 2 + c2;
            int k0 = c * 32 + kb;
            v8u o;
            #pragma unroll
            for (int i = 0; i < 8; ++i) {
                int k = k0 + i;
                float v = 0.f;
                if (j < J) v = (k < DIM) ? sw[j * DIM + k] : nw[j * DIM + (k - DIM)];
                o[i] = f2bf(v);
            }
            *(v8u*)(ob + ((size_t)((t * 8 + c) * 64 + lane)) * 8) = o;
        }
    }
}

// ---------------- bin: local column-prefix of parts -> bases; place edges (LDS atomics only) ----------------
__global__ __launch_bounds__(256) void k_bin(const int* __restrict__ src,
                                             const int* __restrict__ dst,
                                             const int* __restrict__ parts,
                                             unsigned int* __restrict__ packed) {
    __shared__ int s[256], gb[NBK], cnt[NBK];
    const int t = threadIdx.x;
    const int j = blockIdx.x;
    int ct = 0, cp = 0;
    for (int i = 0; i < NBIN; ++i) {
        int v = (t < NBK) ? parts[i * NBK + t] : 0;
        if (i == j) cp = ct;
        ct += v;
    }
    s[t] = ct;
    __syncthreads();
    for (int off = 1; off < 256; off <<= 1) {
        int u = (t >= off) ? s[t - off] : 0;
        __syncthreads();
        s[t] += u;
        __syncthreads();
    }
    if (t < NBK) { gb[t] = (s[t] - ct) + cp; cnt[t] = 0; } // bucket base + own-block offset
    __syncthreads();
    const int e0 = j * EPB;
    const int ecnt = min(EPB, N_EDGES - e0);
    for (int r = t; r < ecnt; r += 256) {
        int sv = src[e0 + r], d = dst[e0 + r];
        int b = d >> 8;
        int loc = atomicAdd(&cnt[b], 1); // LDS
        packed[gb[b] + loc] = ((unsigned int)sv << 8) | (unsigned int)(d & 255);
    }
}

// ---------------- place: local bucket scan + per-node hist -> row_ptr, scatter src_sorted ----------------
__global__ __launch_bounds__(256) void k_place(const unsigned int* __restrict__ packed,
                                               const int* __restrict__ parts,
                                               int* __restrict__ row_ptr,
                                               int* __restrict__ src_sorted) {
    __shared__ int s[256], baseL[NBK], totL[NBK];
    __shared__ int hist[256], cur[256];
    const int b = blockIdx.x, t = threadIdx.x;
    int ct = 0;
    for (int i = 0; i < NBIN; ++i)
        ct += (t < NBK) ? parts[i * NBK + t] : 0;
    s[t] = ct;
    hist[t] = 0;
    __syncthreads();
    for (int off = 1; off < 256; off <<= 1) {
        int u = (t >= off) ? s[t - off] : 0;
        __syncthreads();
        s[t] += u;
        __syncthreads();
    }
    if (t < NBK) { baseL[t] = s[t] - ct; totL[t] = ct; }
    __syncthreads();
    const int base = baseL[b], cb = totL[b];
    for (int i = t; i < cb; i += 256)
        atomicAdd(&hist[packed[base + i] & 255u], 1); // LDS, ~16 avg per counter
    __syncthreads();
    int v = hist[t];
    s[t] = v;
    __syncthreads();
    for (int off = 1; off < 256; off <<= 1) {
        int u = (t >= off) ? s[t - off] : 0;
        __syncthreads();
        s[t] += u;
        __syncthreads();
    }
    int excl = base + s[t] - v;
    int node = b * 256 + t;
    if (node < N_NODES) row_ptr[node] = excl;
    if (b == NBK - 1 && t == 255) row_ptr[N_NODES] = base + cb; // == N_EDGES
    cur[t] = excl;
    __syncthreads();
    for (int i = t; i < cb; i += 256) {
        unsigned int pkt = packed[base + i];
        int pos = atomicAdd(&cur[pkt & 255u], 1);
        src_sorted[pos] = (int)(pkt >> 8); // lands in this bucket's ~16KB region
    }
}

// ---------------- fused layer: self-load + mean-aggregate -> LDS A-tile, then MFMA GEMM ----------------
// R8 base (verified 238us) with the gather main loop deepened 4 -> 8 loads in flight using a
// SINGLE accumulator set (R5's dual-acc + guards spilled at 64 VGPR; this is straight-line,
// +16 transient VGPRs only, per-lane edge order identical to R8). R11's persistent grid-barrier
// variant was 577us (per-block device fences = per-block L2 flush) -- abandoned.
static __device__ __forceinline__ void acc16(v2f* acc, uint4 u) {
    acc[0] += __builtin_amdgcn_cvt_pk_f32_fp8(u.x, false);
    acc[1] += __builtin_amdgcn_cvt_pk_f32_fp8(u.x, true);
    acc[2] += __builtin_amdgcn_cvt_pk_f32_fp8(u.y, false);
    acc[3] += __builtin_amdgcn_cvt_pk_f32_fp8(u.y, true);
    acc[4] += __builtin_amdgcn_cvt_pk_f32_fp8(u.z, false);
    acc[5] += __builtin_amdgcn_cvt_pk_f32_fp8(u.z, true);
    acc[6] += __builtin_amdgcn_cvt_pk_f32_fp8(u.w, false);
    acc[7] += __builtin_amdgcn_cvt_pk_f32_fp8(u.w, true);
}

template <int NT, bool RELU, bool OUTBF>
__global__ __launch_bounds__(256, 4) void k_layer(const unsigned short* __restrict__ Ab,
                                                  const unsigned char* __restrict__ g8,
                                                  const int* __restrict__ row_ptr,
                                                  const int* __restrict__ srcs,
                                                  const unsigned short* __restrict__ Wf,
                                                  const float* __restrict__ bias,
                                                  void* __restrict__ out,
                                                  unsigned char* __restrict__ out8,
                                                  int outdim) {
    __shared__ unsigned short Alds[64 * 256]; // 32 KB: [row][0..128)=self, [128..256)=mean, XOR-swizzled
    const int tid = threadIdx.x;
    const int m0 = blockIdx.x * 64;
    // ---- self half -> LDS ----
    #pragma unroll
    for (int i = 0; i < 4; ++i) {
        int t = tid + 256 * i;           // 0..1023
        int row = t >> 4, ch = t & 15;   // 64 rows x 16 chunks of 8 shorts
        int node = m0 + row; if (node >= N_NODES) node = N_NODES - 1;
        v8u v = *(const v8u*)(Ab + (size_t)node * DIM + ch * 8);
        *(v8u*)(Alds + row * 256 + ((ch * 8) ^ ((row & 7) * 8))) = v;
    }
    // ---- mean half: gather fp8 rows, 4 nodes per wave-pass, 2x8-lane halves per node ----
    const int lane = tid & 63, wv = tid >> 6;
    const int gg = lane & 7;          // 8 lanes span the 128B row, 16B each
    const int sub = (lane >> 3) & 1;  // which edge of a pair this half handles
    const int ns = lane >> 4;         // node slot within wave
    for (int pass = 0; pass < 4; ++pass) {
        const int row = wv * 16 + pass * 4 + ns; // 0..63
        const int n = m0 + row;
        int start = 0, end = 0;
        if (n < N_NODES) { start = row_ptr[n]; end = row_ptr[n + 1]; }
        v2f ga[8] = {};
        int e = start;
        // main loop: 16 edges / iteration, 8 independent 16B loads in flight per lane
        int s0, s1, s2, s3, s4, s5, s6, s7;
        bool have = (e + 16 <= end);
        if (have) {
            s0 = srcs[e + sub];      s1 = srcs[e + 2 + sub];
            s2 = srcs[e + 4 + sub];  s3 = srcs[e + 6 + sub];
            s4 = srcs[e + 8 + sub];  s5 = srcs[e + 10 + sub];
            s6 = srcs[e + 12 + sub]; s7 = srcs[e + 14 + sub];
        }
        while (have) {
            uint4 u0 = *(const uint4*)(g8 + (size_t)s0 * DIM + gg * 16);
            uint4 u1 = *(const uint4*)(g8 + (size_t)s1 * DIM + gg * 16);
            uint4 u2 = *(const uint4*)(g8 + (size_t)s2 * DIM + gg * 16);
            uint4 u3 = *(const uint4*)(g8 + (size_t)s3 * DIM + gg * 16);
            uint4 u4 = *(const uint4*)(g8 + (size_t)s4 * DIM + gg * 16);
            uint4 u5 = *(const uint4*)(g8 + (size_t)s5 * DIM + gg * 16);
            uint4 u6 = *(const uint4*)(g8 + (size_t)s6 * DIM + gg * 16);
            uint4 u7 = *(const uint4*)(g8 + (size_t)s7 * DIM + gg * 16);
            e += 16;
            have = (e + 16 <= end);
            if (have) { // prefetch next indices while gathers are in flight
                s0 = srcs[e + sub];      s1 = srcs[e + 2 + sub];
                s2 = srcs[e + 4 + sub];  s3 = srcs[e + 6 + sub];
                s4 = srcs[e + 8 + sub];  s5 = srcs[e + 10 + sub];
                s6 = srcs[e + 12 + sub]; s7 = srcs[e + 14 + sub];
            }
            acc16(ga, u0); acc16(ga, u1); acc16(ga, u2); acc16(ga, u3);
            acc16(ga, u4); acc16(ga, u5); acc16(ga, u6); acc16(ga, u7);
        }
        if (e + 8 <= end) {
            int t0 = srcs[e + sub],     t1 = srcs[e + 2 + sub];
            int t2 = srcs[e + 4 + sub], t3 = srcs[e + 6 + sub];
            uint4 u0 = *(const uint4*)(g8 + (size_t)t0 * DIM + gg * 16);
            uint4 u1 = *(const uint4*)(g8 + (size_t)t1 * DIM + gg * 16);
            uint4 u2 = *(const uint4*)(g8 + (size_t)t2 * DIM + gg * 16);
            uint4 u3 = *(const uint4*)(g8 + (size_t)t3 * DIM + gg * 16);
            acc16(ga, u0); acc16(ga, u1); acc16(ga, u2); acc16(ga, u3);
            e += 8;
        }
        if (e + 4 <= end) {
            int t0 = srcs[e + sub], t1 = srcs[e + 2 + sub];
            uint4 u0 = *(const uint4*)(g8 + (size_t)t0 * DIM + gg * 16);
            uint4 u1 = *(const uint4*)(g8 + (size_t)t1 * DIM + gg * 16);
            acc16(ga, u0); acc16(ga, u1);
            e += 4;
        }
        if (e + 2 <= end) {
            int t0 = srcs[e + sub];
            uint4 u0 = *(const uint4*)(g8 + (size_t)t0 * DIM + gg * 16);
            acc16(ga, u0);
            e += 2;
        }
        if (e < end && sub == 0) { // odd leftover edge: even half only
            int t0 = srcs[e];
            uint4 u0 = *(const uint4*)(g8 + (size_t)t0 * DIM + gg * 16);
            acc16(ga, u0);
        }
        #pragma unroll
        for (int i = 0; i < 8; ++i) {
            ga[i][0] += __shfl_xor(ga[i][0], 8);
            ga[i][1] += __shfl_xor(ga[i][1], 8);
        }
        int d = end - start;
        float inv = (d > 0) ? 1.f / (float)d : 0.f;
        v2f w0 = sub ? ga[4] : ga[0];
        v2f w1 = sub ? ga[5] : ga[1];
        v2f w2 = sub ? ga[6] : ga[2];
        v2f w3 = sub ? ga[7] : ga[3];
        v8u o;
        o[0] = f2bf(w0[0] * inv); o[1] = f2bf(w0[1] * inv);
        o[2] = f2bf(w1[0] * inv); o[3] = f2bf(w1[1] * inv);
        o[4] = f2bf(w2[0] * inv); o[5] = f2bf(w2[1] * inv);
        o[6] = f2bf(w3[0] * inv); o[7] = f2bf(w3[1] * inv);
        *(v8u*)(Alds + row * 256 + ((DIM + gg * 16 + sub * 8) ^ ((row & 7) * 8))) = o;
    }
    __syncthreads();
    // ---- MFMA: A from LDS, W fragments streamed from L2 (1KB coalesced per wave-load) ----
    const int m = lane & 15, qd = lane >> 4;
    const int arow = wv * 16 + m;
    v4f acc[NT] = {};
    #pragma unroll
    for (int c = 0; c < 8; ++c) {
        const int koff = c * 32 + qd * 8;
        v8s af = *(const v8s*)(Alds + arow * 256 + (koff ^ ((arow & 7) * 8)));
        #pragma unroll
        for (int t = 0; t < NT; ++t) {
            v8s wf = *(const v8s*)(Wf + ((size_t)((t * 8 + c) * 64 + lane)) * 8);
            acc[t] = __builtin_amdgcn_mfma_f32_16x16x32_bf16(af, wf, acc[t], 0, 0, 0);
        }
    }
    // ---- epilogue ----
    #pragma unroll
    for (int t = 0; t < NT; ++t) {
        int col = t * 16 + m;
        bool colok = (col < outdim);
        float bv = colok ? bias[col] : 0.f;
        #pragma unroll
        for (int r = 0; r < 4; ++r) {
            int nrow = m0 + wv * 16 + qd * 4 + r;
            if (colok && nrow < N_NODES) {
                float v = acc[t][r] + bv;
                if (RELU) v = fmaxf(v, 0.f);
                size_t idx = (size_t)nrow * outdim + col;
                if (OUTBF) {
                    ((unsigned short*)out)[idx] = f2bf(v);
                    out8[idx] = f2fp8(v);
                } else {
                    ((float*)out)[idx] = v;
                }
            }
        }
    }
}

extern "C" void kernel_launch(void* const* d_in, const int* in_sizes, int n_in,
                              void* d_out, int out_size, void* d_ws, size_t ws_size,
                              hipStream_t stream) {
    const float* x   = (const float*)d_in[0];
    const int*   src = (const int*)d_in[1];
    const int*   dst = (const int*)d_in[2];
    const float* ws1 = (const float*)d_in[3];
    const float* wn1 = (const float*)d_in[4];
    const float* b1  = (const float*)d_in[5];
    const float* ws2 = (const float*)d_in[6];
    const float* wn2 = (const float*)d_in[7];
    const float* b2  = (const float*)d_in[8];
    const float* ws3 = (const float*)d_in[9];
    const float* wn3 = (const float*)d_in[10];
    const float* b3  = (const float*)d_in[11];

    char* p = (char*)d_ws;
    auto alloc = [&](size_t bytes) { char* r = p; p += (bytes + 255) & ~(size_t)255; return r; };
    int*   row_ptr = (int*)alloc((size_t)(N_NODES + 1) * 4);
    int*   srcs    = (int*)alloc((size_t)N_EDGES * 4);
    unsigned int* packed = (unsigned int*)alloc((size_t)N_EDGES * 4);
    int*   parts   = (int*)alloc((size_t)NBIN * NBK * 4);
    unsigned short* xb  = (unsigned short*)alloc((size_t)N_NODES * DIM * 2);
    unsigned short* h1b = (unsigned short*)alloc((size_t)N_NODES * DIM * 2);
    unsigned short* h2b = (unsigned short*)alloc((size_t)N_NODES * DIM * 2);
    unsigned char*  h8a = (unsigned char*)alloc((size_t)N_NODES * DIM);
    unsigned char*  h8b = (unsigned char*)alloc((size_t)N_NODES * DIM);
    unsigned short* wf1 = (unsigned short*)alloc((size_t)8 * 8 * 64 * 8 * 2);
    unsigned short* wf2 = (unsigned short*)alloc((size_t)8 * 8 * 64 * 8 * 2);
    unsigned short* wf3 = (unsigned short*)alloc((size_t)3 * 8 * 64 * 8 * 2);

    // 1: conversions + bucket hist partials (no global atomics, no memsets)
    k_prep<<<XCVT_NB + NBIN + WFNB, 256, 0, stream>>>(
        x, xb, (unsigned int*)h8a, dst, parts,
        ws1, wn1, ws2, wn2, ws3, wn3, wf1, wf2, wf3);
    // 2-3: CSR (bucket prefix recomputed locally in each kernel; no serial scan dispatch)
    k_bin<<<NBIN, 256, 0, stream>>>(src, dst, parts, packed);
    k_place<<<NBK, 256, 0, stream>>>(packed, parts, row_ptr, srcs);

    const int MB = (N_NODES + 63) / 64; // 782

    // fused layers: agg + GEMM in one kernel each; fp8 table ping-pongs h8a <-> h8b
    k_layer<8, true, true><<<MB, 256, 0, stream>>>(xb,  h8a, row_ptr, srcs, wf1, b1, h1b, h8b, DIM);
    k_layer<8, true, true><<<MB, 256, 0, stream>>>(h1b, h8b, row_ptr, srcs, wf2, b2, h2b, h8a, DIM);
    k_layer<3, false, false><<<MB, 256, 0, stream>>>(h2b, h8a, row_ptr, srcs, wf3, b3, d_out, nullptr, OUTD);
}

// Round 25
// 231.644 us; speedup vs baseline: 2.4909x; 1.0582x over previous
//
#include <hip/hip_runtime.h>

#define N_NODES 50000
#define N_EDGES 800000
#define DIM 128
#define OUTD 47
#define NBK 196                          // dst buckets of 256 nodes
#define EPB 4096                         // edges per histogram/bin block
#define NBIN ((N_EDGES + EPB - 1) / EPB) // 196
#define XCVT_NB (N_NODES * DIM / 8 / 256) // 3125 blocks, 8 elems/thread
#define WFNB 19                          // weight-fragment tiles: 8 + 8 + 3

typedef __attribute__((ext_vector_type(8))) short v8s;
typedef __attribute__((ext_vector_type(8))) unsigned short v8u;
typedef __attribute__((ext_vector_type(4))) float v4f;
typedef __attribute__((ext_vector_type(2))) float v2f;

static __device__ __forceinline__ unsigned short f2bf(float f) {
    union { float f; unsigned int u; } v; v.f = f;
    unsigned int x = v.u;
    return (unsigned short)((x + 0x7fffu + ((x >> 16) & 1u)) >> 16); // RNE
}
static __device__ __forceinline__ unsigned char f2fp8(float f) {
    unsigned int pk = __builtin_amdgcn_cvt_pk_fp8_f32(f, f, 0, false);
    return (unsigned char)(pk & 0xffu);
}

// ---------------- prep: x->bf16+fp8 | per-block bucket hist partials | weight fragment cvt ----------------
// Weights emitted PRE-SWIZZLED into MFMA B-fragment order:
//   frag(t, c): lane l holds W[j = t*16 + (l&15)][k = c*32 + (l>>4)*8 + i], i=0..7 (bf16 x8, 16B)
//   stored at ob[((t*8 + c)*64 + l)*8 + i]  -> a wave's fragment read is 1KB contiguous.
__global__ __launch_bounds__(256) void k_prep(const float* __restrict__ x,
                                              unsigned short* __restrict__ xb,
                                              unsigned int* __restrict__ x8,
                                              const int* __restrict__ dst,
                                              int* __restrict__ parts,
                                              const float* __restrict__ ws1, const float* __restrict__ wn1,
                                              const float* __restrict__ ws2, const float* __restrict__ wn2,
                                              const float* __restrict__ ws3, const float* __restrict__ wn3,
                                              unsigned short* __restrict__ wf1,
                                              unsigned short* __restrict__ wf2,
                                              unsigned short* __restrict__ wf3) {
    __shared__ int hist[NBK];
    const int bx = blockIdx.x, tid = threadIdx.x;
    if (bx < XCVT_NB) {
        int i = bx * 256 + tid; // 8 elems per thread
        float4 v0 = ((const float4*)x)[i * 2];
        float4 v1 = ((const float4*)x)[i * 2 + 1];
        ushort4 o0, o1;
        o0.x = f2bf(v0.x); o0.y = f2bf(v0.y); o0.z = f2bf(v0.z); o0.w = f2bf(v0.w);
        o1.x = f2bf(v1.x); o1.y = f2bf(v1.y); o1.z = f2bf(v1.z); o1.w = f2bf(v1.w);
        ((ushort4*)xb)[i * 2] = o0;
        ((ushort4*)xb)[i * 2 + 1] = o1;
        unsigned int a = __builtin_amdgcn_cvt_pk_fp8_f32(v0.x, v0.y, 0, false);
        a = __builtin_amdgcn_cvt_pk_fp8_f32(v0.z, v0.w, a, true);
        unsigned int b = __builtin_amdgcn_cvt_pk_fp8_f32(v1.x, v1.y, 0, false);
        b = __builtin_amdgcn_cvt_pk_fp8_f32(v1.z, v1.w, b, true);
        uint2 o; o.x = a; o.y = b;
        ((uint2*)x8)[i] = o;
    } else if (bx < XCVT_NB + NBIN) {
        const int j = bx - XCVT_NB;
        for (int i = tid; i < NBK; i += 256) hist[i] = 0;
        __syncthreads();
        const int e0 = j * EPB;
        const int ecnt = min(EPB, N_EDGES - e0);
        for (int r = tid; r < ecnt; r += 256)
            atomicAdd(&hist[dst[e0 + r] >> 8], 1); // LDS only
        __syncthreads();
        for (int i = tid; i < NBK; i += 256) parts[j * NBK + i] = hist[i];
    } else {
        int b2 = bx - XCVT_NB - NBIN; // fragment tile
        const float *sw, *nw; unsigned short* ob; int t, J;
        if (b2 < 8)       { sw = ws1; nw = wn1; ob = wf1; t = b2;      J = DIM; }
        else if (b2 < 16) { sw = ws2; nw = wn2; ob = wf2; t = b2 - 8;  J = DIM; }
        else              { sw = ws3; nw = wn3; ob = wf3; t = b2 - 16; J = OUTD; }
        const int lane = tid & 63, cp = tid >> 6;
        const int j = t * 16 + (lane & 15);
        const int kb = (lane >> 4) * 8;
        #pragma unroll
        for (int c2 = 0; c2 < 2; ++c2) {
            int c = cp * 2 + c2;
            int k0 = c * 32 + kb;
            v8u o;
            #pragma unroll
            for (int i = 0; i < 8; ++i) {
                int k = k0 + i;
                float v = 0.f;
                if (j < J) v = (k < DIM) ? sw[j * DIM + k] : nw[j * DIM + (k - DIM)];
                o[i] = f2bf(v);
            }
            *(v8u*)(ob + ((size_t)((t * 8 + c) * 64 + lane)) * 8) = o;
        }
    }
}

// ---------------- bin: local column-prefix of parts -> bases; place edges (LDS atomics only) ----------------
// Block 0 additionally publishes the bucket prefix (baseL/totL) to global so k_place
// doesn't recompute the 196-iteration parts column sum + scan.
__global__ __launch_bounds__(256) void k_bin(const int* __restrict__ src,
                                             const int* __restrict__ dst,
                                             const int* __restrict__ parts,
                                             unsigned int* __restrict__ packed,
                                             int* __restrict__ gbase,
                                             int* __restrict__ gtot) {
    __shared__ int s[256], gb[NBK], cnt[NBK];
    const int t = threadIdx.x;
    const int j = blockIdx.x;
    int ct = 0, cp = 0;
    for (int i = 0; i < NBIN; ++i) {
        int v = (t < NBK) ? parts[i * NBK + t] : 0;
        if (i == j) cp = ct;
        ct += v;
    }
    s[t] = ct;
    __syncthreads();
    for (int off = 1; off < 256; off <<= 1) {
        int u = (t >= off) ? s[t - off] : 0;
        __syncthreads();
        s[t] += u;
        __syncthreads();
    }
    if (t < NBK) {
        gb[t] = (s[t] - ct) + cp; cnt[t] = 0; // bucket base + own-block offset
        if (j == 0) { gbase[t] = s[t] - ct; gtot[t] = ct; } // handoff to k_place
    }
    __syncthreads();
    const int e0 = j * EPB;
    const int ecnt = min(EPB, N_EDGES - e0);
    for (int r = t; r < ecnt; r += 256) {
        int sv = src[e0 + r], d = dst[e0 + r];
        int b = d >> 8;
        int loc = atomicAdd(&cnt[b], 1); // LDS
        packed[gb[b] + loc] = ((unsigned int)sv << 8) | (unsigned int)(d & 255);
    }
}

// ---------------- place: per-node hist -> row_ptr, scatter src_sorted ----------------
// Bucket prefix read directly from k_bin's handoff (no parts recompute, no first scan).
__global__ __launch_bounds__(256) void k_place(const unsigned int* __restrict__ packed,
                                               const int* __restrict__ gbase,
                                               const int* __restrict__ gtot,
                                               int* __restrict__ row_ptr,
                                               int* __restrict__ src_sorted) {
    __shared__ int s[256];
    __shared__ int hist[256], cur[256];
    const int b = blockIdx.x, t = threadIdx.x;
    hist[t] = 0;
    __syncthreads();
    const int base = gbase[b], cb = gtot[b]; // scalar loads, L2-hot
    for (int i = t; i < cb; i += 256)
        atomicAdd(&hist[packed[base + i] & 255u], 1); // LDS, ~16 avg per counter
    __syncthreads();
    int v = hist[t];
    s[t] = v;
    __syncthreads();
    for (int off = 1; off < 256; off <<= 1) {
        int u = (t >= off) ? s[t - off] : 0;
        __syncthreads();
        s[t] += u;
        __syncthreads();
    }
    int excl = base + s[t] - v;
    int node = b * 256 + t;
    if (node < N_NODES) row_ptr[node] = excl;
    if (b == NBK - 1 && t == 255) row_ptr[N_NODES] = base + cb; // == N_EDGES
    cur[t] = excl;
    __syncthreads();
    for (int i = t; i < cb; i += 256) {
        unsigned int pkt = packed[base + i];
        int pos = atomicAdd(&cur[pkt & 255u], 1);
        src_sorted[pos] = (int)(pkt >> 8); // lands in this bucket's ~16KB region
    }
}

// ---------------- fused layer: self-load + mean-aggregate -> LDS A-tile, then MFMA GEMM ----------------
// R8's verified k_layer (238us): 4-deep gather + register-light index prefetch.
// Probed and rejected: 2x issue width (R1 null), dual-chain MLP (R5 spill), 8-deep unroll
// (R17: 245us, slight regression) -- per-wave gather MLP is NOT the limiter beyond depth 4.
static __device__ __forceinline__ void acc16(v2f* acc, uint4 u) {
    acc[0] += __builtin_amdgcn_cvt_pk_f32_fp8(u.x, false);
    acc[1] += __builtin_amdgcn_cvt_pk_f32_fp8(u.x, true);
    acc[2] += __builtin_amdgcn_cvt_pk_f32_fp8(u.y, false);
    acc[3] += __builtin_amdgcn_cvt_pk_f32_fp8(u.y, true);
    acc[4] += __builtin_amdgcn_cvt_pk_f32_fp8(u.z, false);
    acc[5] += __builtin_amdgcn_cvt_pk_f32_fp8(u.z, true);
    acc[6] += __builtin_amdgcn_cvt_pk_f32_fp8(u.w, false);
    acc[7] += __builtin_amdgcn_cvt_pk_f32_fp8(u.w, true);
}

template <int NT, bool RELU, bool OUTBF>
__global__ __launch_bounds__(256, 4) void k_layer(const unsigned short* __restrict__ Ab,
                                                  const unsigned char* __restrict__ g8,
                                                  const int* __restrict__ row_ptr,
                                                  const int* __restrict__ srcs,
                                                  const unsigned short* __restrict__ Wf,
                                                  const float* __restrict__ bias,
                                                  void* __restrict__ out,
                                                  unsigned char* __restrict__ out8,
                                                  int outdim) {
    __shared__ unsigned short Alds[64 * 256]; // 32 KB: [row][0..128)=self, [128..256)=mean, XOR-swizzled
    const int tid = threadIdx.x;
    const int m0 = blockIdx.x * 64;
    // ---- self half -> LDS ----
    #pragma unroll
    for (int i = 0; i < 4; ++i) {
        int t = tid + 256 * i;           // 0..1023
        int row = t >> 4, ch = t & 15;   // 64 rows x 16 chunks of 8 shorts
        int node = m0 + row; if (node >= N_NODES) node = N_NODES - 1;
        v8u v = *(const v8u*)(Ab + (size_t)node * DIM + ch * 8);
        *(v8u*)(Alds + row * 256 + ((ch * 8) ^ ((row & 7) * 8))) = v;
    }
    // ---- mean half: gather fp8 rows, 4 nodes per wave-pass, 2x8-lane halves per node ----
    const int lane = tid & 63, wv = tid >> 6;
    const int gg = lane & 7;          // 8 lanes span the 128B row, 16B each
    const int sub = (lane >> 3) & 1;  // which edge of a pair this half handles
    const int ns = lane >> 4;         // node slot within wave
    for (int pass = 0; pass < 4; ++pass) {
        const int row = wv * 16 + pass * 4 + ns; // 0..63
        const int n = m0 + row;
        int start = 0, end = 0;
        if (n < N_NODES) { start = row_ptr[n]; end = row_ptr[n + 1]; }
        v2f ga[8] = {};
        int e = start;
        int s0, s1, s2, s3;
        bool have = (e + 8 <= end);
        if (have) {
            s0 = srcs[e + sub]; s1 = srcs[e + 2 + sub];
            s2 = srcs[e + 4 + sub]; s3 = srcs[e + 6 + sub];
        }
        while (have) {
            uint4 u0 = *(const uint4*)(g8 + (size_t)s0 * DIM + gg * 16);
            uint4 u1 = *(const uint4*)(g8 + (size_t)s1 * DIM + gg * 16);
            uint4 u2 = *(const uint4*)(g8 + (size_t)s2 * DIM + gg * 16);
            uint4 u3 = *(const uint4*)(g8 + (size_t)s3 * DIM + gg * 16);
            e += 8;
            have = (e + 8 <= end);
            if (have) { // prefetch next indices while gathers are in flight
                s0 = srcs[e + sub]; s1 = srcs[e + 2 + sub];
                s2 = srcs[e + 4 + sub]; s3 = srcs[e + 6 + sub];
            }
            acc16(ga, u0); acc16(ga, u1); acc16(ga, u2); acc16(ga, u3);
        }
        if (e + 4 <= end) {
            int t0 = srcs[e + sub], t1 = srcs[e + 2 + sub];
            uint4 u0 = *(const uint4*)(g8 + (size_t)t0 * DIM + gg * 16);
            uint4 u1 = *(const uint4*)(g8 + (size_t)t1 * DIM + gg * 16);
            acc16(ga, u0); acc16(ga, u1);
            e += 4;
        }
        if (e + 2 <= end) {
            int t0 = srcs[e + sub];
            uint4 u0 = *(const uint4*)(g8 + (size_t)t0 * DIM + gg * 16);
            acc16(ga, u0);
            e += 2;
        }
        if (e < end && sub == 0) { // odd leftover edge: even half only
            int t0 = srcs[e];
            uint4 u0 = *(const uint4*)(g8 + (size_t)t0 * DIM + gg * 16);
            acc16(ga, u0);
        }
        #pragma unroll
        for (int i = 0; i < 8; ++i) {
            ga[i][0] += __shfl_xor(ga[i][0], 8);
            ga[i][1] += __shfl_xor(ga[i][1], 8);
        }
        int d = end - start;
        float inv = (d > 0) ? 1.f / (float)d : 0.f;
        v2f w0 = sub ? ga[4] : ga[0];
        v2f w1 = sub ? ga[5] : ga[1];
        v2f w2 = sub ? ga[6] : ga[2];
        v2f w3 = sub ? ga[7] : ga[3];
        v8u o;
        o[0] = f2bf(w0[0] * inv); o[1] = f2bf(w0[1] * inv);
        o[2] = f2bf(w1[0] * inv); o[3] = f2bf(w1[1] * inv);
        o[4] = f2bf(w2[0] * inv); o[5] = f2bf(w2[1] * inv);
        o[6] = f2bf(w3[0] * inv); o[7] = f2bf(w3[1] * inv);
        *(v8u*)(Alds + row * 256 + ((DIM + gg * 16 + sub * 8) ^ ((row & 7) * 8))) = o;
    }
    __syncthreads();
    // ---- MFMA: A from LDS, W fragments streamed from L2 (1KB coalesced per wave-load) ----
    const int m = lane & 15, qd = lane >> 4;
    const int arow = wv * 16 + m;
    v4f acc[NT] = {};
    #pragma unroll
    for (int c = 0; c < 8; ++c) {
        const int koff = c * 32 + qd * 8;
        v8s af = *(const v8s*)(Alds + arow * 256 + (koff ^ ((arow & 7) * 8)));
        #pragma unroll
        for (int t = 0; t < NT; ++t) {
            v8s wf = *(const v8s*)(Wf + ((size_t)((t * 8 + c) * 64 + lane)) * 8);
            acc[t] = __builtin_amdgcn_mfma_f32_16x16x32_bf16(af, wf, acc[t], 0, 0, 0);
        }
    }
    // ---- epilogue ----
    #pragma unroll
    for (int t = 0; t < NT; ++t) {
        int col = t * 16 + m;
        bool colok = (col < outdim);
        float bv = colok ? bias[col] : 0.f;
        #pragma unroll
        for (int r = 0; r < 4; ++r) {
            int nrow = m0 + wv * 16 + qd * 4 + r;
            if (colok && nrow < N_NODES) {
                float v = acc[t][r] + bv;
                if (RELU) v = fmaxf(v, 0.f);
                size_t idx = (size_t)nrow * outdim + col;
                if (OUTBF) {
                    ((unsigned short*)out)[idx] = f2bf(v);
                    out8[idx] = f2fp8(v);
                } else {
                    ((float*)out)[idx] = v;
                }
            }
        }
    }
}

extern "C" void kernel_launch(void* const* d_in, const int* in_sizes, int n_in,
                              void* d_out, int out_size, void* d_ws, size_t ws_size,
                              hipStream_t stream) {
    const float* x   = (const float*)d_in[0];
    const int*   src = (const int*)d_in[1];
    const int*   dst = (const int*)d_in[2];
    const float* ws1 = (const float*)d_in[3];
    const float* wn1 = (const float*)d_in[4];
    const float* b1  = (const float*)d_in[5];
    const float* ws2 = (const float*)d_in[6];
    const float* wn2 = (const float*)d_in[7];
    const float* b2  = (const float*)d_in[8];
    const float* ws3 = (const float*)d_in[9];
    const float* wn3 = (const float*)d_in[10];
    const float* b3  = (const float*)d_in[11];

    char* p = (char*)d_ws;
    auto alloc = [&](size_t bytes) { char* r = p; p += (bytes + 255) & ~(size_t)255; return r; };
    int*   row_ptr = (int*)alloc((size_t)(N_NODES + 1) * 4);
    int*   srcs    = (int*)alloc((size_t)N_EDGES * 4);
    unsigned int* packed = (unsigned int*)alloc((size_t)N_EDGES * 4);
    int*   parts   = (int*)alloc((size_t)NBIN * NBK * 4);
    int*   gbase   = (int*)alloc((size_t)NBK * 4);
    int*   gtot    = (int*)alloc((size_t)NBK * 4);
    unsigned short* xb  = (unsigned short*)alloc((size_t)N_NODES * DIM * 2);
    unsigned short* h1b = (unsigned short*)alloc((size_t)N_NODES * DIM * 2);
    unsigned short* h2b = (unsigned short*)alloc((size_t)N_NODES * DIM * 2);
    unsigned char*  h8a = (unsigned char*)alloc((size_t)N_NODES * DIM);
    unsigned char*  h8b = (unsigned char*)alloc((size_t)N_NODES * DIM);
    unsigned short* wf1 = (unsigned short*)alloc((size_t)8 * 8 * 64 * 8 * 2);
    unsigned short* wf2 = (unsigned short*)alloc((size_t)8 * 8 * 64 * 8 * 2);
    unsigned short* wf3 = (unsigned short*)alloc((size_t)3 * 8 * 64 * 8 * 2);

    // 1: conversions + bucket hist partials (no global atomics, no memsets)
    k_prep<<<XCVT_NB + NBIN + WFNB, 256, 0, stream>>>(
        x, xb, (unsigned int*)h8a, dst, parts,
        ws1, wn1, ws2, wn2, ws3, wn3, wf1, wf2, wf3);
    // 2-3: CSR (k_bin publishes bucket prefix; k_place consumes it directly)
    k_bin<<<NBIN, 256, 0, stream>>>(src, dst, parts, packed, gbase, gtot);
    k_place<<<NBK, 256, 0, stream>>>(packed, gbase, gtot, row_ptr, srcs);

    const int MB = (N_NODES + 63) / 64; // 782

    // fused layers: agg + GEMM in one kernel each; fp8 table ping-pongs h8a <-> h8b
    k_layer<8, true, true><<<MB, 256, 0, stream>>>(xb,  h8a, row_ptr, srcs, wf1, b1, h1b, h8b, DIM);
    k_layer<8, true, true><<<MB, 256, 0, stream>>>(h1b, h8b, row_ptr, srcs, wf2, b2, h2b, h8a, DIM);
    k_layer<3, false, false><<<MB, 256, 0, stream>>>(h2b, h8a, row_ptr, srcs, wf3, b3, d_out, nullptr, OUTD);
}